// Round 11
// baseline (140.430 us; speedup 1.0000x reference)
//
#include <hip/hip_runtime.h>
#include <hip/hip_bf16.h>

#define BATCH 16
#define SEQ   2048
#define DK    128
#define NT    16                    // steps per segment (512 kv / 32)
#define SC2   0.12751744f           // (1/sqrt(128)) * log2(e) -- folded into K prepass
#define THRL2 11.541560f            // defer-max threshold (= 8*log2e)

typedef __attribute__((ext_vector_type(8)))  short short8v;
typedef __attribute__((ext_vector_type(4)))  float float4v;
typedef __attribute__((ext_vector_type(16))) float float16v;

typedef const __attribute__((address_space(1))) unsigned int* gas_t;
typedef __attribute__((address_space(3))) unsigned int* las_t;

__device__ inline void gl_lds16(const void* g, void* l) {
    __builtin_amdgcn_global_load_lds((gas_t)g, (las_t)l, 16, 0, 0);
}

__device__ inline short f2bf(float f) {
    __hip_bfloat16 h = __float2bfloat16(f);
    unsigned short u;
    __builtin_memcpy(&u, &h, sizeof(u));
    return (short)u;
}

__device__ inline unsigned cvt_pk_bf16(float a, float b) {
    unsigned r;
    asm("v_cvt_pk_bf16_f32 %0, %1, %2" : "=v"(r) : "v"(a), "v"(b));
    return r;   // lo = bf16(a), hi = bf16(b)
}

// -------- prepass: K fp32 -> bf16 * (scale*log2e)  (row-major) --------
__global__ __launch_bounds__(256)
void conv_k_kernel(const float* __restrict__ k, short* __restrict__ kb)
{
    size_t i = ((size_t)blockIdx.x * 256 + threadIdx.x) * 8;
    float4 a = *reinterpret_cast<const float4*>(k + i);
    float4 b = *reinterpret_cast<const float4*>(k + i + 4);
    short8v t;
    t[0] = f2bf(a.x * SC2); t[1] = f2bf(a.y * SC2); t[2] = f2bf(a.z * SC2); t[3] = f2bf(a.w * SC2);
    t[4] = f2bf(b.x * SC2); t[5] = f2bf(b.y * SC2); t[6] = f2bf(b.z * SC2); t[7] = f2bf(b.w * SC2);
    *reinterpret_cast<short8v*>(kb + i) = t;
}

// -------- prepass: V fp32 [b][s][d] -> bf16 Vt [b][d][col] ------------
// psi-interleave per 16-kv group: V[kv] stored at col = base16 | pos,
// pos = 8*((kv>>2)&1) + 4*((kv>>3)&1) + (kv&3): 32x32-MFMA PV A-frag
// (packed P regs) matches contiguous 16B B-fragment units.
__global__ __launch_bounds__(256)
void transpose_v_kernel(const float* __restrict__ v, short* __restrict__ vt)
{
    __shared__ float tile[32][33];
    const int tx = threadIdx.x & 31;
    const int ty = threadIdx.x >> 5;              // 0..7
    const int b  = blockIdx.z;
    const int s0 = blockIdx.x * 32;
    const int d0 = blockIdx.y * 32;

    const float* vb = v + ((size_t)b * SEQ + s0) * DK + d0;
#pragma unroll
    for (int i = 0; i < 4; ++i) {
        int r = ty + 8 * i;
        tile[r][tx] = vb[(size_t)r * DK + tx];
    }
    __syncthreads();

    const int s   = s0 + tx;
    const int kvl = s & 15;
    const int pos = (((kvl >> 2) & 1) << 3) | (((kvl >> 3) & 1) << 2) | (kvl & 3);
    const size_t col = (size_t)(s & ~15) | pos;

    short* vtb = vt + ((size_t)b * DK + d0) * SEQ;
#pragma unroll
    for (int i = 0; i < 4; ++i) {
        int r = ty + 8 * i;                       // d offset
        vtb[(size_t)r * SEQ + col] = f2bf(tile[tx][r]);
    }
}

// ---------------- main: 16-wave flash attention (4 waves/SIMD) --------
// Grid 256 (XCD-decoded: each XCD owns 2 batches -> staging L2-local,
// FETCH == compulsory, r8-verified).  Block = 1024 thr = 16 waves:
// qt = wave&3 (32 q rows), h = wave>>2 (kv segment of 512, 16 steps).
// One block/CU (LDS 130KB) = 16 waves/CU = 4 waves/SIMD: LDS/VALU/MFMA
// phases of different waves overlap between barriers (r8 had only 2/SIMD
// and the pipes serialized: wall ~= sum of pipe times).
// Per-wave step code identical to r8 (92 VGPR measured; 16-wave block
// caps at 128 -> no spill headroom issue).  r10 lesson: dual-q spilled
// (WRITE 16->35MB); falsifier here is WRITE_SIZE >> 16.4MB.
// K tile [32 kv][256B,16 slots], read slot ^= (kr&15).
// V tile d-pair packed [64 R][128B,8 slots], slot w = (dh*4+u) ^ (R&7).
// QK^T = mfma32(K,Q); PV = mfma32(P,V); O rows = crow(reg,hi).
// Epilogue: 2-round LDS merge tree over 4 segments (8x16KB regions).
__global__ __launch_bounds__(1024)
void attn_fwd_v11(const float* __restrict__ q,
                  const short* __restrict__ kb,
                  const short* __restrict__ vt,
                  float* __restrict__ out)
{
    __shared__ __align__(16) char lds[133120];   // 2x64KB staging; merge aliases + 2KB m/l

    const int tid  = threadIdx.x;
    const int lane = tid & 63;
    const int wave = tid >> 6;         // 0..15
    const int qt   = wave & 3;
    const int h    = wave >> 2;        // kv segment 0..3
    const int bid  = blockIdx.x;
    const int work = (bid & 7) * 32 + (bid >> 3);   // XCD-grouped
    const int b    = work >> 4;
    const int q0   = (work & 15) * 128 + qt * 32;

    const int l31 = lane & 31;
    const int hi  = lane >> 5;

    // ---- Q fragments: qf[s] = Q[q0+l31][s*16 + hi*8 + 0..7] ----
    const float* qrow = q + ((size_t)b * SEQ + q0 + l31) * DK + hi * 8;
    short8v qf[8];
#pragma unroll
    for (int s = 0; s < 8; ++s) {
        float4 x = *reinterpret_cast<const float4*>(qrow + s * 16);
        float4 y = *reinterpret_cast<const float4*>(qrow + s * 16 + 4);
        union { unsigned u[4]; short8v v; } pk;
        pk.u[0] = cvt_pk_bf16(x.x, x.y);
        pk.u[1] = cvt_pk_bf16(x.z, x.w);
        pk.u[2] = cvt_pk_bf16(y.x, y.y);
        pk.u[3] = cvt_pk_bf16(y.z, y.w);
        qf[s] = pk.v;
    }

    const char* kB = (const char*)(kb + (size_t)b * SEQ * DK);   // 256B rows
    const char* vB = (const char*)(vt + (size_t)b * DK * SEQ);   // 4096B rows

    // ---- staging: waves 0..7 -> K (2 waves/seg), waves 8..15 -> V ----
    const char* src[4];
    int dstoff[4];
    long sstep;
    if (wave < 8) {
        const int seg = wave >> 1, p = wave & 1;
#pragma unroll
        for (int i = 0; i < 4; ++i) {
            const int cc = p * 4 + i;                     // chunk 0..7
            const int kr = cc * 4 + (lane >> 4);          // kv row 0..31
            src[i] = kB + (size_t)(seg * 512 + kr) * 256
                        + (((lane & 15) ^ (kr & 15)) << 4);
            dstoff[i] = seg * 16384 + cc * 1024;
        }
        sstep = 32 * 256;
    } else {
        const int seg = (wave - 8) >> 1, p = wave & 1;
#pragma unroll
        for (int i = 0; i < 4; ++i) {
            const int cc   = p * 4 + i;                   // chunk 0..7
            const int R    = cc * 8 + (lane >> 3);        // R row 0..63 (d pair)
            const int unit = (lane & 7) ^ (R & 7);
            const int d    = 2 * R + (unit >> 2);
            src[i] = vB + (size_t)d * 4096 + seg * 1024 + (unit & 3) * 16;
            dstoff[i] = seg * 16384 + 8192 + cc * 1024;
        }
        sstep = 32 * 2;
    }

    float m_run = -1e30f;
    float l_run = 0.0f;
    float16v o[4];
#pragma unroll
    for (int dblk = 0; dblk < 4; ++dblk)
#pragma unroll
        for (int i = 0; i < 16; ++i) o[dblk][i] = 0.f;

    auto STAGE = [&](int bufsel, int t) {
        char* base = lds + bufsel * 65536;
#pragma unroll
        for (int i = 0; i < 4; ++i)
            gl_lds16(src[i] + (size_t)t * sstep, base + dstoff[i]);
    };

    STAGE(0, 0);
    __syncthreads();

    int buf = 0;
    for (int t = 0; t < NT; ++t) {
        if (t + 1 < NT) STAGE(buf ^ 1, t + 1);

        const char* Kl = lds + buf * 65536 + h * 16384;
        const char* Vl = Kl + 8192;
        const char* ka = Kl + l31 * 256;

        // ---- QK^T: one 32-kv subtile over D=128 ----
        float16v sa;
#pragma unroll
        for (int i = 0; i < 16; ++i) sa[i] = 0.f;
        __builtin_amdgcn_s_setprio(1);
#pragma unroll
        for (int s = 0; s < 8; ++s) {
            const int un = ((2 * s + hi) ^ (l31 & 15)) << 4;
            short8v kf = *reinterpret_cast<const short8v*>(ka + un);
            sa = __builtin_amdgcn_mfma_f32_32x32x16_bf16(kf, qf[s], sa, 0, 0, 0);
        }
        __builtin_amdgcn_s_setprio(0);

        // ---- online softmax (log2-domain; defer-max) ----
        float mx = sa[0];
#pragma unroll
        for (int i = 1; i < 16; ++i) mx = fmaxf(mx, sa[i]);
        mx = fmaxf(mx, __shfl_xor(mx, 32));

        if (!__all(mx <= m_run + THRL2)) {
            const float mnew  = fmaxf(m_run, mx);
            const float alpha = exp2f(m_run - mnew);
            l_run *= alpha;
            m_run = mnew;
            float aq[16];
#pragma unroll
            for (int reg = 0; reg < 16; ++reg)
                aq[reg] = __shfl(alpha, (reg & 3) + 8 * (reg >> 2) + 4 * hi);
#pragma unroll
            for (int dblk = 0; dblk < 4; ++dblk)
#pragma unroll
                for (int reg = 0; reg < 16; ++reg) o[dblk][reg] *= aq[reg];
        }

        float ts = 0.f;
#pragma unroll
        for (int i = 0; i < 16; ++i) {
            const float e = exp2f(sa[i] - m_run);
            sa[i] = e;
            ts += e;
        }
        ts += __shfl_xor(ts, 32);
        l_run += ts;

        // ---- P -> bf16 A-fragments (psi-order: pf[g] = packed p-regs) ----
        short8v pf[2];
#pragma unroll
        for (int g = 0; g < 2; ++g) {
            const int r0 = g * 8;
            union { unsigned u[4]; short8v v; } pk;
            pk.u[0] = cvt_pk_bf16(sa[r0 + 0], sa[r0 + 1]);
            pk.u[1] = cvt_pk_bf16(sa[r0 + 2], sa[r0 + 3]);
            pk.u[2] = cvt_pk_bf16(sa[r0 + 4], sa[r0 + 5]);
            pk.u[3] = cvt_pk_bf16(sa[r0 + 6], sa[r0 + 7]);
            pf[g] = pk.v;
        }

        // ---- PV: B frag = one b128 from d-pair-packed V tile ----
        __builtin_amdgcn_s_setprio(1);
#pragma unroll
        for (int dblk = 0; dblk < 4; ++dblk) {
            const int R  = dblk * 16 + (l31 >> 1);
            const char* vr = Vl + R * 128;
            const int dh4 = (l31 & 1) << 2;
#pragma unroll
            for (int g = 0; g < 2; ++g) {
                const int w = ((dh4 | (2 * g + hi)) ^ (R & 7)) << 4;
                short8v vf = *reinterpret_cast<const short8v*>(vr + w);
                o[dblk] = __builtin_amdgcn_mfma_f32_32x32x16_bf16(pf[g], vf, o[dblk], 0, 0, 0);
            }
        }
        __builtin_amdgcn_s_setprio(0);

        __syncthreads();       // drains staged loads + LDS reads
        buf ^= 1;
    }

    // ---- 2-round merge tree over the 4 segments (aliases staging LDS) ----
    // regions: rid*16KB O-data (8 regions); m/l at 131072 + rid*256B.
    auto WRITE_REGION = [&](int rid) {
        float* ro = (float*)(lds + rid * 16384);
        float* ml = (float*)(lds + 131072) + rid * 64;
#pragma unroll
        for (int dblk = 0; dblk < 4; ++dblk)
#pragma unroll
            for (int reg = 0; reg < 16; ++reg) {
                const int qp = (reg & 3) + 8 * (reg >> 2) + 4 * hi;
                ro[qp * 128 + dblk * 32 + l31] = o[dblk][reg];
            }
        if (hi == 0) {
            ml[l31 * 2]     = m_run;
            ml[l31 * 2 + 1] = l_run;
        }
    };

    auto MERGE_FROM = [&](int rid) {
        float* ro = (float*)(lds + rid * 16384);
        float* ml = (float*)(lds + 131072) + rid * 64;
        const float m1 = ml[l31 * 2];
        const float l1 = ml[l31 * 2 + 1];
        const float mf = fmaxf(m_run, m1);
        const float a0 = exp2f(m_run - mf);
        const float a1 = exp2f(m1 - mf);
        l_run = l_run * a0 + l1 * a1;
        m_run = mf;
        float a0q[16], a1q[16];
#pragma unroll
        for (int reg = 0; reg < 16; ++reg) {
            const int qp = (reg & 3) + 8 * (reg >> 2) + 4 * hi;
            a0q[reg] = __shfl(a0, qp);
            a1q[reg] = __shfl(a1, qp);
        }
#pragma unroll
        for (int dblk = 0; dblk < 4; ++dblk)
#pragma unroll
            for (int reg = 0; reg < 16; ++reg) {
                const int qp = (reg & 3) + 8 * (reg >> 2) + 4 * hi;
                o[dblk][reg] = o[dblk][reg] * a0q[reg]
                             + ro[qp * 128 + dblk * 32 + l31] * a1q[reg];
            }
    };

    // main loop ended with __syncthreads -> LDS idle, all waves aligned
    if (h == 1 || h == 3) WRITE_REGION(qt + 4 * (h >> 1));
    __syncthreads();
    if (h == 0 || h == 2) MERGE_FROM(qt + 4 * (h >> 1));
    __syncthreads();
    if (h == 2) WRITE_REGION(qt);
    __syncthreads();
    if (h == 0) {
        MERGE_FROM(qt);
        const float li = 1.0f / l_run;
        float liq[16];
#pragma unroll
        for (int reg = 0; reg < 16; ++reg) {
            const int qp = (reg & 3) + 8 * (reg >> 2) + 4 * hi;
            liq[reg] = __shfl(li, qp);
        }
        float* ob = out + ((size_t)b * SEQ + q0) * DK;
#pragma unroll
        for (int dblk = 0; dblk < 4; ++dblk)
#pragma unroll
            for (int reg = 0; reg < 16; ++reg) {
                const int qp = (reg & 3) + 8 * (reg >> 2) + 4 * hi;
                ob[(size_t)qp * DK + dblk * 32 + l31] = o[dblk][reg] * liq[reg];
            }
    }
}

// ---------------- fallback (round-1 kernel) if ws too small -----------
__global__ __launch_bounds__(256)
void attn_fwd_slow(const float* __restrict__ q,
                   const float* __restrict__ k,
                   const float* __restrict__ v,
                   float* __restrict__ out)
{
    const int lane = threadIdx.x & 63;
    const int wave = threadIdx.x >> 6;
    const int b    = blockIdx.y;
    const int q0   = blockIdx.x * 64 + wave * 16;
    const int row = lane & 15;
    const int grp = lane >> 4;

    const float* qb = q + ((size_t)b * SEQ + q0) * DK;
    const float* kbp = k + (size_t)b * SEQ * DK;
    const float* vbp = v + (size_t)b * SEQ * DK;

    short8v qf[4];
#pragma unroll
    for (int c = 0; c < 4; ++c) {
        const float* p = qb + row * DK + c * 32 + grp * 8;
        float4 x = *reinterpret_cast<const float4*>(p);
        float4 y = *reinterpret_cast<const float4*>(p + 4);
        short8v t;
        t[0] = f2bf(x.x); t[1] = f2bf(x.y); t[2] = f2bf(x.z); t[3] = f2bf(x.w);
        t[4] = f2bf(y.x); t[5] = f2bf(y.y); t[6] = f2bf(y.z); t[7] = f2bf(y.w);
        qf[c] = t;
    }

    float m_run = -1e30f, l_run = 0.0f;
    float4v o[8];
#pragma unroll
    for (int i = 0; i < 8; ++i) { o[i][0]=0.f; o[i][1]=0.f; o[i][2]=0.f; o[i][3]=0.f; }
    const float scale = 0.08838834764831845f;

    for (int kv0 = 0; kv0 < SEQ; kv0 += 16) {
        short8v kf[4];
        const float* kp0 = kbp + (size_t)(kv0 + row) * DK + grp * 8;
#pragma unroll
        for (int c = 0; c < 4; ++c) {
            const float* p = kp0 + c * 32;
            float4 x = *reinterpret_cast<const float4*>(p);
            float4 y = *reinterpret_cast<const float4*>(p + 4);
            short8v t;
            t[0] = f2bf(x.x); t[1] = f2bf(x.y); t[2] = f2bf(x.z); t[3] = f2bf(x.w);
            t[4] = f2bf(y.x); t[5] = f2bf(y.y); t[6] = f2bf(y.z); t[7] = f2bf(y.w);
            kf[c] = t;
        }
        short8v vf[8];
#pragma unroll
        for (int dblk = 0; dblk < 8; ++dblk) {
            const float* p = vbp + (size_t)(kv0 + 4 * grp) * DK + dblk * 16 + row;
            short b0 = f2bf(p[0]);
            short b1 = f2bf(p[DK]);
            short b2 = f2bf(p[2 * DK]);
            short b3 = f2bf(p[3 * DK]);
            short8v t;
            t[0]=b0; t[1]=b1; t[2]=b2; t[3]=b3; t[4]=b0; t[5]=b1; t[6]=b2; t[7]=b3;
            vf[dblk] = t;
        }
        float4v s; s[0]=0.f; s[1]=0.f; s[2]=0.f; s[3]=0.f;
#pragma unroll
        for (int c = 0; c < 4; ++c)
            s = __builtin_amdgcn_mfma_f32_16x16x32_bf16(kf[c], qf[c], s, 0, 0, 0);

        float sv[4]; float tmax = -1e30f;
#pragma unroll
        for (int r = 0; r < 4; ++r) { sv[r] = s[r] * scale; tmax = fmaxf(tmax, sv[r]); }
        tmax = fmaxf(tmax, __shfl_xor(tmax, 16));
        tmax = fmaxf(tmax, __shfl_xor(tmax, 32));
        const float mnew = fmaxf(m_run, tmax);
        float pr[4]; float tsum = 0.f;
#pragma unroll
        for (int r = 0; r < 4; ++r) { pr[r] = __expf(sv[r] - mnew); tsum += pr[r]; }
        tsum += __shfl_xor(tsum, 16);
        tsum += __shfl_xor(tsum, 32);
        const float alpha = __expf(m_run - mnew);
        l_run = l_run * alpha + tsum;
        m_run = mnew;
        float aq[4];
#pragma unroll
        for (int r = 0; r < 4; ++r) aq[r] = __shfl(alpha, grp * 4 + r);
#pragma unroll
        for (int dblk = 0; dblk < 8; ++dblk)
#pragma unroll
            for (int r = 0; r < 4; ++r) o[dblk][r] *= aq[r];

        short8v pfv;
        pfv[0]=f2bf(pr[0]); pfv[1]=f2bf(pr[1]); pfv[2]=f2bf(pr[2]); pfv[3]=f2bf(pr[3]);
        pfv[4]=0; pfv[5]=0; pfv[6]=0; pfv[7]=0;
#pragma unroll
        for (int dblk = 0; dblk < 8; ++dblk)
            o[dblk] = __builtin_amdgcn_mfma_f32_16x16x32_bf16(pfv, vf[dblk], o[dblk], 0, 0, 0);
    }

    const float linv = 1.0f / l_run;
    float li[4];
#pragma unroll
    for (int r = 0; r < 4; ++r) li[r] = __shfl(linv, grp * 4 + r);
    float* ob = out + ((size_t)b * SEQ + q0) * DK;
#pragma unroll
    for (int dblk = 0; dblk < 8; ++dblk)
#pragma unroll
        for (int r = 0; r < 4; ++r)
            ob[(size_t)(grp * 4 + r) * DK + dblk * 16 + row] = o[dblk][r] * li[r];
}

extern "C" void kernel_launch(void* const* d_in, const int* in_sizes, int n_in,
                              void* d_out, int out_size, void* d_ws, size_t ws_size,
                              hipStream_t stream) {
    const float* q = (const float*)d_in[0];
    const float* k = (const float*)d_in[1];
    const float* v = (const float*)d_in[2];
    float* out = (float*)d_out;

    const size_t kb_bytes = (size_t)BATCH * SEQ * DK * sizeof(short);
    const size_t need = 2 * kb_bytes;

    if (ws_size >= need) {
        short* kb = (short*)d_ws;
        short* vt = (short*)((char*)d_ws + kb_bytes);
        hipLaunchKernelGGL(conv_k_kernel, dim3(2048), dim3(256), 0, stream, k, kb);
        hipLaunchKernelGGL(transpose_v_kernel, dim3(SEQ / 32, DK / 32, BATCH), dim3(256), 0, stream, v, vt);
        hipLaunchKernelGGL(attn_fwd_v11, dim3((SEQ / 128) * BATCH), dim3(1024), 0, stream, q, kb, vt, out);
    } else {
        hipLaunchKernelGGL(attn_fwd_slow, dim3(SEQ / 64, BATCH), dim3(256), 0, stream, q, k, v, out);
    }
}

// Round 12
// 139.891 us; speedup vs baseline: 1.0039x; 1.0039x over previous
//
#include <hip/hip_runtime.h>
#include <hip/hip_bf16.h>

#define BATCH 16
#define SEQ   2048
#define DK    128
#define NT    16                    // steps per segment (512 kv / 32)
#define SC2   0.12751744f           // (1/sqrt(128)) * log2(e) -- folded into K prepass
#define THRL2 11.541560f            // defer-max threshold (= 8*log2e)

typedef __attribute__((ext_vector_type(8)))  short short8v;
typedef __attribute__((ext_vector_type(4)))  float float4v;
typedef __attribute__((ext_vector_type(16))) float float16v;

typedef const __attribute__((address_space(1))) unsigned int* gas_t;
typedef __attribute__((address_space(3))) unsigned int* las_t;

__device__ inline void gl_lds16(const void* g, void* l) {
    __builtin_amdgcn_global_load_lds((gas_t)g, (las_t)l, 16, 0, 0);
}

__device__ inline short f2bf(float f) {
    __hip_bfloat16 h = __float2bfloat16(f);
    unsigned short u;
    __builtin_memcpy(&u, &h, sizeof(u));
    return (short)u;
}

__device__ inline unsigned cvt_pk_bf16(float a, float b) {
    unsigned r;
    asm("v_cvt_pk_bf16_f32 %0, %1, %2" : "=v"(r) : "v"(a), "v"(b));
    return r;   // lo = bf16(a), hi = bf16(b)
}

// -------- prepass: K fp32 -> bf16 * (scale*log2e)  (row-major) --------
__global__ __launch_bounds__(256)
void conv_k_kernel(const float* __restrict__ k, short* __restrict__ kb)
{
    size_t i = ((size_t)blockIdx.x * 256 + threadIdx.x) * 8;
    float4 a = *reinterpret_cast<const float4*>(k + i);
    float4 b = *reinterpret_cast<const float4*>(k + i + 4);
    short8v t;
    t[0] = f2bf(a.x * SC2); t[1] = f2bf(a.y * SC2); t[2] = f2bf(a.z * SC2); t[3] = f2bf(a.w * SC2);
    t[4] = f2bf(b.x * SC2); t[5] = f2bf(b.y * SC2); t[6] = f2bf(b.z * SC2); t[7] = f2bf(b.w * SC2);
    *reinterpret_cast<short8v*>(kb + i) = t;
}

// -------- prepass: V fp32 [b][s][d] -> bf16 Vt [b][d][col] ------------
// psi-interleave per 16-kv group: V[kv] stored at col = base16 | pos,
// pos = 8*((kv>>2)&1) + 4*((kv>>3)&1) + (kv&3): 32x32-MFMA PV A-frag
// (packed P regs) matches contiguous 16B B-fragment units.
__global__ __launch_bounds__(256)
void transpose_v_kernel(const float* __restrict__ v, short* __restrict__ vt)
{
    __shared__ float tile[32][33];
    const int tx = threadIdx.x & 31;
    const int ty = threadIdx.x >> 5;              // 0..7
    const int b  = blockIdx.z;
    const int s0 = blockIdx.x * 32;
    const int d0 = blockIdx.y * 32;

    const float* vb = v + ((size_t)b * SEQ + s0) * DK + d0;
#pragma unroll
    for (int i = 0; i < 4; ++i) {
        int r = ty + 8 * i;
        tile[r][tx] = vb[(size_t)r * DK + tx];
    }
    __syncthreads();

    const int s   = s0 + tx;
    const int kvl = s & 15;
    const int pos = (((kvl >> 2) & 1) << 3) | (((kvl >> 3) & 1) << 2) | (kvl & 3);
    const size_t col = (size_t)(s & ~15) | pos;

    short* vtb = vt + ((size_t)b * DK + d0) * SEQ;
#pragma unroll
    for (int i = 0; i < 4; ++i) {
        int r = ty + 8 * i;                       // d offset
        vtb[(size_t)r * SEQ + col] = f2bf(tile[tx][r]);
    }
}

// ---------------- main: 16-wave flash attention (4 waves/SIMD) --------
// Grid 256 (XCD-decoded: each XCD owns 2 batches -> staging L2-local,
// FETCH == compulsory, r8-verified).  Block = 1024 thr = 16 waves:
// qt = wave&3 (32 q rows), h = wave>>2 (kv segment of 512, 16 steps).
// One block/CU (LDS 130KB) = 16 waves/CU = 4 waves/SIMD.
// __launch_bounds__(1024, 4): 4 waves/EU * 4 EU / 16 waves = 1 block/CU,
// VGPR cap = 512/4 = 128 >= the 92 this kernel needs.  r11 lesson: bare
// (1024) let the compiler target 8 waves/EU -> 64-VGPR cap -> full spill
// (WRITE 16->89MB).  r7 lesson: don't ask for MORE waves than the regs
// allow.  The bound must match the intended occupancy exactly.
// K tile [32 kv][256B,16 slots], read slot ^= (kr&15).
// V tile d-pair packed [64 R][128B,8 slots], slot w = (dh*4+u) ^ (R&7).
// QK^T = mfma32(K,Q); PV = mfma32(P,V); O rows = crow(reg,hi).
// Epilogue: 2-round LDS merge tree over 4 segments (8x16KB regions).
__global__ __launch_bounds__(1024, 4)
void attn_fwd_v12(const float* __restrict__ q,
                  const short* __restrict__ kb,
                  const short* __restrict__ vt,
                  float* __restrict__ out)
{
    __shared__ __align__(16) char lds[133120];   // 2x64KB staging; merge aliases + 2KB m/l

    const int tid  = threadIdx.x;
    const int lane = tid & 63;
    const int wave = tid >> 6;         // 0..15
    const int qt   = wave & 3;
    const int h    = wave >> 2;        // kv segment 0..3
    const int bid  = blockIdx.x;
    const int work = (bid & 7) * 32 + (bid >> 3);   // XCD-grouped
    const int b    = work >> 4;
    const int q0   = (work & 15) * 128 + qt * 32;

    const int l31 = lane & 31;
    const int hi  = lane >> 5;

    // ---- Q fragments: qf[s] = Q[q0+l31][s*16 + hi*8 + 0..7] ----
    const float* qrow = q + ((size_t)b * SEQ + q0 + l31) * DK + hi * 8;
    short8v qf[8];
#pragma unroll
    for (int s = 0; s < 8; ++s) {
        float4 x = *reinterpret_cast<const float4*>(qrow + s * 16);
        float4 y = *reinterpret_cast<const float4*>(qrow + s * 16 + 4);
        union { unsigned u[4]; short8v v; } pk;
        pk.u[0] = cvt_pk_bf16(x.x, x.y);
        pk.u[1] = cvt_pk_bf16(x.z, x.w);
        pk.u[2] = cvt_pk_bf16(y.x, y.y);
        pk.u[3] = cvt_pk_bf16(y.z, y.w);
        qf[s] = pk.v;
    }

    const char* kB = (const char*)(kb + (size_t)b * SEQ * DK);   // 256B rows
    const char* vB = (const char*)(vt + (size_t)b * DK * SEQ);   // 4096B rows

    // ---- staging: waves 0..7 -> K (2 waves/seg), waves 8..15 -> V ----
    const char* src[4];
    int dstoff[4];
    long sstep;
    if (wave < 8) {
        const int seg = wave >> 1, p = wave & 1;
#pragma unroll
        for (int i = 0; i < 4; ++i) {
            const int cc = p * 4 + i;                     // chunk 0..7
            const int kr = cc * 4 + (lane >> 4);          // kv row 0..31
            src[i] = kB + (size_t)(seg * 512 + kr) * 256
                        + (((lane & 15) ^ (kr & 15)) << 4);
            dstoff[i] = seg * 16384 + cc * 1024;
        }
        sstep = 32 * 256;
    } else {
        const int seg = (wave - 8) >> 1, p = wave & 1;
#pragma unroll
        for (int i = 0; i < 4; ++i) {
            const int cc   = p * 4 + i;                   // chunk 0..7
            const int R    = cc * 8 + (lane >> 3);        // R row 0..63 (d pair)
            const int unit = (lane & 7) ^ (R & 7);
            const int d    = 2 * R + (unit >> 2);
            src[i] = vB + (size_t)d * 4096 + seg * 1024 + (unit & 3) * 16;
            dstoff[i] = seg * 16384 + 8192 + cc * 1024;
        }
        sstep = 32 * 2;
    }

    float m_run = -1e30f;
    float l_run = 0.0f;
    float16v o[4];
#pragma unroll
    for (int dblk = 0; dblk < 4; ++dblk)
#pragma unroll
        for (int i = 0; i < 16; ++i) o[dblk][i] = 0.f;

    auto STAGE = [&](int bufsel, int t) {
        char* base = lds + bufsel * 65536;
#pragma unroll
        for (int i = 0; i < 4; ++i)
            gl_lds16(src[i] + (size_t)t * sstep, base + dstoff[i]);
    };

    STAGE(0, 0);
    __syncthreads();

    int buf = 0;
    for (int t = 0; t < NT; ++t) {
        if (t + 1 < NT) STAGE(buf ^ 1, t + 1);

        const char* Kl = lds + buf * 65536 + h * 16384;
        const char* Vl = Kl + 8192;
        const char* ka = Kl + l31 * 256;

        // ---- QK^T: one 32-kv subtile over D=128 ----
        float16v sa;
#pragma unroll
        for (int i = 0; i < 16; ++i) sa[i] = 0.f;
        __builtin_amdgcn_s_setprio(1);
#pragma unroll
        for (int s = 0; s < 8; ++s) {
            const int un = ((2 * s + hi) ^ (l31 & 15)) << 4;
            short8v kf = *reinterpret_cast<const short8v*>(ka + un);
            sa = __builtin_amdgcn_mfma_f32_32x32x16_bf16(kf, qf[s], sa, 0, 0, 0);
        }
        __builtin_amdgcn_s_setprio(0);

        // ---- online softmax (log2-domain; defer-max) ----
        float mx = sa[0];
#pragma unroll
        for (int i = 1; i < 16; ++i) mx = fmaxf(mx, sa[i]);
        mx = fmaxf(mx, __shfl_xor(mx, 32));

        if (!__all(mx <= m_run + THRL2)) {
            const float mnew  = fmaxf(m_run, mx);
            const float alpha = exp2f(m_run - mnew);
            l_run *= alpha;
            m_run = mnew;
            float aq[16];
#pragma unroll
            for (int reg = 0; reg < 16; ++reg)
                aq[reg] = __shfl(alpha, (reg & 3) + 8 * (reg >> 2) + 4 * hi);
#pragma unroll
            for (int dblk = 0; dblk < 4; ++dblk)
#pragma unroll
                for (int reg = 0; reg < 16; ++reg) o[dblk][reg] *= aq[reg];
        }

        float ts = 0.f;
#pragma unroll
        for (int i = 0; i < 16; ++i) {
            const float e = exp2f(sa[i] - m_run);
            sa[i] = e;
            ts += e;
        }
        ts += __shfl_xor(ts, 32);
        l_run += ts;

        // ---- P -> bf16 A-fragments (psi-order: pf[g] = packed p-regs) ----
        short8v pf[2];
#pragma unroll
        for (int g = 0; g < 2; ++g) {
            const int r0 = g * 8;
            union { unsigned u[4]; short8v v; } pk;
            pk.u[0] = cvt_pk_bf16(sa[r0 + 0], sa[r0 + 1]);
            pk.u[1] = cvt_pk_bf16(sa[r0 + 2], sa[r0 + 3]);
            pk.u[2] = cvt_pk_bf16(sa[r0 + 4], sa[r0 + 5]);
            pk.u[3] = cvt_pk_bf16(sa[r0 + 6], sa[r0 + 7]);
            pf[g] = pk.v;
        }

        // ---- PV: B frag = one b128 from d-pair-packed V tile ----
        __builtin_amdgcn_s_setprio(1);
#pragma unroll
        for (int dblk = 0; dblk < 4; ++dblk) {
            const int R  = dblk * 16 + (l31 >> 1);
            const char* vr = Vl + R * 128;
            const int dh4 = (l31 & 1) << 2;
#pragma unroll
            for (int g = 0; g < 2; ++g) {
                const int w = ((dh4 | (2 * g + hi)) ^ (R & 7)) << 4;
                short8v vf = *reinterpret_cast<const short8v*>(vr + w);
                o[dblk] = __builtin_amdgcn_mfma_f32_32x32x16_bf16(pf[g], vf, o[dblk], 0, 0, 0);
            }
        }
        __builtin_amdgcn_s_setprio(0);

        __syncthreads();       // drains staged loads + LDS reads
        buf ^= 1;
    }

    // ---- 2-round merge tree over the 4 segments (aliases staging LDS) ----
    // regions: rid*16KB O-data (8 regions); m/l at 131072 + rid*256B.
    auto WRITE_REGION = [&](int rid) {
        float* ro = (float*)(lds + rid * 16384);
        float* ml = (float*)(lds + 131072) + rid * 64;
#pragma unroll
        for (int dblk = 0; dblk < 4; ++dblk)
#pragma unroll
            for (int reg = 0; reg < 16; ++reg) {
                const int qp = (reg & 3) + 8 * (reg >> 2) + 4 * hi;
                ro[qp * 128 + dblk * 32 + l31] = o[dblk][reg];
            }
        if (hi == 0) {
            ml[l31 * 2]     = m_run;
            ml[l31 * 2 + 1] = l_run;
        }
    };

    auto MERGE_FROM = [&](int rid) {
        float* ro = (float*)(lds + rid * 16384);
        float* ml = (float*)(lds + 131072) + rid * 64;
        const float m1 = ml[l31 * 2];
        const float l1 = ml[l31 * 2 + 1];
        const float mf = fmaxf(m_run, m1);
        const float a0 = exp2f(m_run - mf);
        const float a1 = exp2f(m1 - mf);
        l_run = l_run * a0 + l1 * a1;
        m_run = mf;
        float a0q[16], a1q[16];
#pragma unroll
        for (int reg = 0; reg < 16; ++reg) {
            const int qp = (reg & 3) + 8 * (reg >> 2) + 4 * hi;
            a0q[reg] = __shfl(a0, qp);
            a1q[reg] = __shfl(a1, qp);
        }
#pragma unroll
        for (int dblk = 0; dblk < 4; ++dblk)
#pragma unroll
            for (int reg = 0; reg < 16; ++reg) {
                const int qp = (reg & 3) + 8 * (reg >> 2) + 4 * hi;
                o[dblk][reg] = o[dblk][reg] * a0q[reg]
                             + ro[qp * 128 + dblk * 32 + l31] * a1q[reg];
            }
    };

    // main loop ended with __syncthreads -> LDS idle, all waves aligned
    if (h == 1 || h == 3) WRITE_REGION(qt + 4 * (h >> 1));
    __syncthreads();
    if (h == 0 || h == 2) MERGE_FROM(qt + 4 * (h >> 1));
    __syncthreads();
    if (h == 2) WRITE_REGION(qt);
    __syncthreads();
    if (h == 0) {
        MERGE_FROM(qt);
        const float li = 1.0f / l_run;
        float liq[16];
#pragma unroll
        for (int reg = 0; reg < 16; ++reg) {
            const int qp = (reg & 3) + 8 * (reg >> 2) + 4 * hi;
            liq[reg] = __shfl(li, qp);
        }
        float* ob = out + ((size_t)b * SEQ + q0) * DK;
#pragma unroll
        for (int dblk = 0; dblk < 4; ++dblk)
#pragma unroll
            for (int reg = 0; reg < 16; ++reg) {
                const int qp = (reg & 3) + 8 * (reg >> 2) + 4 * hi;
                ob[(size_t)qp * DK + dblk * 32 + l31] = o[dblk][reg] * liq[reg];
            }
    }
}

// ---------------- fallback (round-1 kernel) if ws too small -----------
__global__ __launch_bounds__(256)
void attn_fwd_slow(const float* __restrict__ q,
                   const float* __restrict__ k,
                   const float* __restrict__ v,
                   float* __restrict__ out)
{
    const int lane = threadIdx.x & 63;
    const int wave = threadIdx.x >> 6;
    const int b    = blockIdx.y;
    const int q0   = blockIdx.x * 64 + wave * 16;
    const int row = lane & 15;
    const int grp = lane >> 4;

    const float* qb = q + ((size_t)b * SEQ + q0) * DK;
    const float* kbp = k + (size_t)b * SEQ * DK;
    const float* vbp = v + (size_t)b * SEQ * DK;

    short8v qf[4];
#pragma unroll
    for (int c = 0; c < 4; ++c) {
        const float* p = qb + row * DK + c * 32 + grp * 8;
        float4 x = *reinterpret_cast<const float4*>(p);
        float4 y = *reinterpret_cast<const float4*>(p + 4);
        short8v t;
        t[0] = f2bf(x.x); t[1] = f2bf(x.y); t[2] = f2bf(x.z); t[3] = f2bf(x.w);
        t[4] = f2bf(y.x); t[5] = f2bf(y.y); t[6] = f2bf(y.z); t[7] = f2bf(y.w);
        qf[c] = t;
    }

    float m_run = -1e30f, l_run = 0.0f;
    float4v o[8];
#pragma unroll
    for (int i = 0; i < 8; ++i) { o[i][0]=0.f; o[i][1]=0.f; o[i][2]=0.f; o[i][3]=0.f; }
    const float scale = 0.08838834764831845f;

    for (int kv0 = 0; kv0 < SEQ; kv0 += 16) {
        short8v kf[4];
        const float* kp0 = kbp + (size_t)(kv0 + row) * DK + grp * 8;
#pragma unroll
        for (int c = 0; c < 4; ++c) {
            const float* p = kp0 + c * 32;
            float4 x = *reinterpret_cast<const float4*>(p);
            float4 y = *reinterpret_cast<const float4*>(p + 4);
            short8v t;
            t[0] = f2bf(x.x); t[1] = f2bf(x.y); t[2] = f2bf(x.z); t[3] = f2bf(x.w);
            t[4] = f2bf(y.x); t[5] = f2bf(y.y); t[6] = f2bf(y.z); t[7] = f2bf(y.w);
            kf[c] = t;
        }
        short8v vf[8];
#pragma unroll
        for (int dblk = 0; dblk < 8; ++dblk) {
            const float* p = vbp + (size_t)(kv0 + 4 * grp) * DK + dblk * 16 + row;
            short b0 = f2bf(p[0]);
            short b1 = f2bf(p[DK]);
            short b2 = f2bf(p[2 * DK]);
            short b3 = f2bf(p[3 * DK]);
            short8v t;
            t[0]=b0; t[1]=b1; t[2]=b2; t[3]=b3; t[4]=b0; t[5]=b1; t[6]=b2; t[7]=b3;
            vf[dblk] = t;
        }
        float4v s; s[0]=0.f; s[1]=0.f; s[2]=0.f; s[3]=0.f;
#pragma unroll
        for (int c = 0; c < 4; ++c)
            s = __builtin_amdgcn_mfma_f32_16x16x32_bf16(kf[c], qf[c], s, 0, 0, 0);

        float sv[4]; float tmax = -1e30f;
#pragma unroll
        for (int r = 0; r < 4; ++r) { sv[r] = s[r] * scale; tmax = fmaxf(tmax, sv[r]); }
        tmax = fmaxf(tmax, __shfl_xor(tmax, 16));
        tmax = fmaxf(tmax, __shfl_xor(tmax, 32));
        const float mnew = fmaxf(m_run, tmax);
        float pr[4]; float tsum = 0.f;
#pragma unroll
        for (int r = 0; r < 4; ++r) { pr[r] = __expf(sv[r] - mnew); tsum += pr[r]; }
        tsum += __shfl_xor(tsum, 16);
        tsum += __shfl_xor(tsum, 32);
        const float alpha = __expf(m_run - mnew);
        l_run = l_run * alpha + tsum;
        m_run = mnew;
        float aq[4];
#pragma unroll
        for (int r = 0; r < 4; ++r) aq[r] = __shfl(alpha, grp * 4 + r);
#pragma unroll
        for (int dblk = 0; dblk < 8; ++dblk)
#pragma unroll
            for (int r = 0; r < 4; ++r) o[dblk][r] *= aq[r];

        short8v pfv;
        pfv[0]=f2bf(pr[0]); pfv[1]=f2bf(pr[1]); pfv[2]=f2bf(pr[2]); pfv[3]=f2bf(pr[3]);
        pfv[4]=0; pfv[5]=0; pfv[6]=0; pfv[7]=0;
#pragma unroll
        for (int dblk = 0; dblk < 8; ++dblk)
            o[dblk] = __builtin_amdgcn_mfma_f32_16x16x32_bf16(pfv, vf[dblk], o[dblk], 0, 0, 0);
    }

    const float linv = 1.0f / l_run;
    float li[4];
#pragma unroll
    for (int r = 0; r < 4; ++r) li[r] = __shfl(linv, grp * 4 + r);
    float* ob = out + ((size_t)b * SEQ + q0) * DK;
#pragma unroll
    for (int dblk = 0; dblk < 8; ++dblk)
#pragma unroll
        for (int r = 0; r < 4; ++r)
            ob[(size_t)(grp * 4 + r) * DK + dblk * 16 + row] = o[dblk][r] * li[r];
}

extern "C" void kernel_launch(void* const* d_in, const int* in_sizes, int n_in,
                              void* d_out, int out_size, void* d_ws, size_t ws_size,
                              hipStream_t stream) {
    const float* q = (const float*)d_in[0];
    const float* k = (const float*)d_in[1];
    const float* v = (const float*)d_in[2];
    float* out = (float*)d_out;

    const size_t kb_bytes = (size_t)BATCH * SEQ * DK * sizeof(short);
    const size_t need = 2 * kb_bytes;

    if (ws_size >= need) {
        short* kb = (short*)d_ws;
        short* vt = (short*)((char*)d_ws + kb_bytes);
        hipLaunchKernelGGL(conv_k_kernel, dim3(2048), dim3(256), 0, stream, k, kb);
        hipLaunchKernelGGL(transpose_v_kernel, dim3(SEQ / 32, DK / 32, BATCH), dim3(256), 0, stream, v, vt);
        hipLaunchKernelGGL(attn_fwd_v12, dim3((SEQ / 128) * BATCH), dim3(1024), 0, stream, q, kb, vt, out);
    } else {
        hipLaunchKernelGGL(attn_fwd_slow, dim3(SEQ / 64, BATCH), dim3(256), 0, stream, q, k, v, out);
    }
}

// Round 13
// 67.781 us; speedup vs baseline: 2.0718x; 2.0639x over previous
//
#include <hip/hip_runtime.h>
#include <hip/hip_bf16.h>

#define BATCH 16
#define SEQ   2048
#define DK    128
#define NT    16                    // kv steps per half (KVBLK=64 over 1024)
#define SC2   0.12751744f           // (1/sqrt(128)) * log2(e) -- folded into K prepass
#define THRL2 11.541560f            // defer-max threshold (= 8*log2e)

typedef __attribute__((ext_vector_type(8)))  short short8v;
typedef __attribute__((ext_vector_type(4)))  float float4v;
typedef __attribute__((ext_vector_type(16))) float float16v;

typedef const __attribute__((address_space(1))) unsigned int* gas_t;
typedef __attribute__((address_space(3))) unsigned int* las_t;

__device__ inline void gl_lds16(const void* g, void* l) {
    __builtin_amdgcn_global_load_lds((gas_t)g, (las_t)l, 16, 0, 0);
}

__device__ inline short f2bf(float f) {
    __hip_bfloat16 h = __float2bfloat16(f);
    unsigned short u;
    __builtin_memcpy(&u, &h, sizeof(u));
    return (short)u;
}

__device__ inline unsigned cvt_pk_bf16(float a, float b) {
    unsigned r;
    asm("v_cvt_pk_bf16_f32 %0, %1, %2" : "=v"(r) : "v"(a), "v"(b));
    return r;   // lo = bf16(a), hi = bf16(b)
}

// -------- prepass: K fp32 -> bf16 * (scale*log2e)  (row-major) --------
__global__ __launch_bounds__(256)
void conv_k_kernel(const float* __restrict__ k, short* __restrict__ kb)
{
    size_t i = ((size_t)blockIdx.x * 256 + threadIdx.x) * 8;
    float4 a = *reinterpret_cast<const float4*>(k + i);
    float4 b = *reinterpret_cast<const float4*>(k + i + 4);
    short8v t;
    t[0] = f2bf(a.x * SC2); t[1] = f2bf(a.y * SC2); t[2] = f2bf(a.z * SC2); t[3] = f2bf(a.w * SC2);
    t[4] = f2bf(b.x * SC2); t[5] = f2bf(b.y * SC2); t[6] = f2bf(b.z * SC2); t[7] = f2bf(b.w * SC2);
    *reinterpret_cast<short8v*>(kb + i) = t;
}

// -------- prepass: V fp32 [b][s][d] -> bf16 Vt [b][d][col] ------------
// psi-interleave per 16-kv group: V[kv] stored at col = base16 | pos,
// pos = 8*((kv>>2)&1) + 4*((kv>>3)&1) + (kv&3), so each 32x32-MFMA PV
// A-fragment {p[r]} r=0..7 matches one contiguous 16B B-fragment unit.
__global__ __launch_bounds__(256)
void transpose_v_kernel(const float* __restrict__ v, short* __restrict__ vt)
{
    __shared__ float tile[32][33];
    const int tx = threadIdx.x & 31;
    const int ty = threadIdx.x >> 5;              // 0..7
    const int b  = blockIdx.z;
    const int s0 = blockIdx.x * 32;
    const int d0 = blockIdx.y * 32;

    const float* vb = v + ((size_t)b * SEQ + s0) * DK + d0;
#pragma unroll
    for (int i = 0; i < 4; ++i) {
        int r = ty + 8 * i;
        tile[r][tx] = vb[(size_t)r * DK + tx];
    }
    __syncthreads();

    const int s   = s0 + tx;
    const int kvl = s & 15;
    const int pos = (((kvl >> 2) & 1) << 3) | (((kvl >> 3) & 1) << 2) | (kvl & 3);
    const size_t col = (size_t)(s & ~15) | pos;

    short* vtb = vt + ((size_t)b * DK + d0) * SEQ;
#pragma unroll
    for (int i = 0; i < 4; ++i) {
        int r = ty + 8 * i;                       // d offset
        vtb[(size_t)r * SEQ + col] = f2bf(tile[tx][r]);
    }
}

// ---------------- main: r6 structure + XCD batch-grouped decode -------
// (r6 was the session-best main kernel: 59.8us, 0 bank conflicts, 108 VGPR.)
// Grid 256 (1D, XCD-decoded): work = (bid&7)*32 + (bid>>3) -> each XCD
// owns 2 batches (K/V 2MB inside its 4MB L2; r8-verified FETCH 75->16.5MB).
// Block = 512 thr = 8 waves: qt = wave&3 (32 q rows), h = wave>>2 (kv half).
// Grid 256 = 1 block/CU; LDS 128KB = 2buf x 2half x (K16K + V16K).
// 2-phase pipeline: STAGE(t+1 -> buf^1) issued BEFORE compute(t); 1 barrier.
// K tile [64 kv][256B], read swizzle unit ^= (row&15)  -> 16 slots, 4-way.
// V tile d-pair packed [64 R][256B], R = d>>1, slot w = ((d&1)<<3|u)^(R&15),
// u = 2g+hi (16B kv-unit, psi-ordered)                  -> 16 slots, 4-way.
// QK^T = mfma32(K, Q): lane q = lane&31 holds S^T rows crow(reg,hi) =
// (reg&3)+8*(reg>>2)+4*hi per 32-kv subtile.  PV = mfma32(P, V).
// __launch_bounds__(512,2): measured 108 VGPR; r7/r11/r12 lessons: any
// tighter occupancy request (",4", 1024-thr blocks) forces 64-VGPR -> spill.
__global__ __launch_bounds__(512, 2)
void attn_fwd_v13(const float* __restrict__ q,
                  const short* __restrict__ kb,
                  const short* __restrict__ vt,
                  float* __restrict__ out)
{
    __shared__ __align__(16) char lds[131072];

    const int tid  = threadIdx.x;
    const int lane = tid & 63;
    const int wave = tid >> 6;         // 0..7
    const int qt   = wave & 3;
    const int h    = wave >> 2;        // kv half
    const int bid  = blockIdx.x;
    const int work = (bid & 7) * 32 + (bid >> 3);   // XCD-grouped
    const int b    = work >> 4;
    const int q0   = (work & 15) * 128 + qt * 32;

    const int l31 = lane & 31;
    const int hi  = lane >> 5;

    // ---- Q fragments: qf[s] = Q[q0+l31][s*16 + hi*8 + 0..7] ----
    const float* qrow = q + ((size_t)b * SEQ + q0 + l31) * DK + hi * 8;
    short8v qf[8];
#pragma unroll
    for (int s = 0; s < 8; ++s) {
        float4 x = *reinterpret_cast<const float4*>(qrow + s * 16);
        float4 y = *reinterpret_cast<const float4*>(qrow + s * 16 + 4);
        union { unsigned u[4]; short8v v; } pk;
        pk.u[0] = cvt_pk_bf16(x.x, x.y);
        pk.u[1] = cvt_pk_bf16(x.z, x.w);
        pk.u[2] = cvt_pk_bf16(y.x, y.y);
        pk.u[3] = cvt_pk_bf16(y.z, y.w);
        qf[s] = pk.v;
    }

    // ---- staging setup: waves 0,1|4,5 -> K; waves 2,3|6,7 -> V ----
    const char* kB = (const char*)(kb + (size_t)b * SEQ * DK);   // 256B rows
    const char* vB = (const char*)(vt + (size_t)b * DK * SEQ);   // 4096B rows
    const int hkv = h * 1024;

    const char* src[8];
    int dstoff[8];
    long sstep;
    if (qt < 2) {
#pragma unroll
        for (int i = 0; i < 8; ++i) {
            const int kr = qt * 32 + i * 4 + (lane >> 4);        // kv row 0..63
            src[i] = kB + (size_t)(hkv + kr) * 256 + (((lane & 15) ^ (kr & 15)) << 4);
            dstoff[i] = h * 32768 + qt * 8192 + i * 1024;
        }
        sstep = 64 * 256;
    } else {
#pragma unroll
        for (int i = 0; i < 8; ++i) {
            const int R  = (qt - 2) * 32 + i * 4 + (lane >> 4);  // R row 0..63
            const int wx = (lane & 15) ^ (R & 15);
            const int d  = 2 * R + (wx >> 3);
            src[i] = vB + (size_t)d * (SEQ * 2) + (size_t)hkv * 2 + ((wx & 7) << 4);
            dstoff[i] = h * 32768 + 16384 + (qt - 2) * 8192 + i * 1024;
        }
        sstep = 64 * 2;
    }

    float m_run = -1e30f;
    float l_run = 0.0f;
    float16v o[4];
#pragma unroll
    for (int dblk = 0; dblk < 4; ++dblk)
#pragma unroll
        for (int i = 0; i < 16; ++i) o[dblk][i] = 0.f;

    auto STAGE = [&](int bufsel, int t) {
        char* base = lds + bufsel * 65536;
#pragma unroll
        for (int i = 0; i < 8; ++i)
            gl_lds16(src[i] + (size_t)t * sstep, base + dstoff[i]);
    };

    STAGE(0, 0);
    __syncthreads();

    int buf = 0;
    for (int t = 0; t < NT; ++t) {
        if (t + 1 < NT) STAGE(buf ^ 1, t + 1);

        const char* Kl = lds + buf * 65536 + h * 32768;
        const char* Vl = Kl + 16384;
        const char* ka = Kl + l31 * 256;

        // ---- QK^T: 2 subtiles of 32 kv over D=128 ----
        float16v sa[2];
#pragma unroll
        for (int i = 0; i < 16; ++i) { sa[0][i] = 0.f; sa[1][i] = 0.f; }
        __builtin_amdgcn_s_setprio(1);
#pragma unroll
        for (int s = 0; s < 8; ++s) {
            const int un = ((2 * s + hi) ^ (l31 & 15)) << 4;
            short8v kf0 = *reinterpret_cast<const short8v*>(ka + un);
            short8v kf1 = *reinterpret_cast<const short8v*>(ka + 8192 + un);
            sa[0] = __builtin_amdgcn_mfma_f32_32x32x16_bf16(kf0, qf[s], sa[0], 0, 0, 0);
            sa[1] = __builtin_amdgcn_mfma_f32_32x32x16_bf16(kf1, qf[s], sa[1], 0, 0, 0);
        }
        __builtin_amdgcn_s_setprio(0);

        // ---- online softmax (log2-domain; defer-max) ----
        float mx = sa[0][0];
#pragma unroll
        for (int i = 1; i < 16; ++i) mx = fmaxf(mx, sa[0][i]);
#pragma unroll
        for (int i = 0; i < 16; ++i) mx = fmaxf(mx, sa[1][i]);
        mx = fmaxf(mx, __shfl_xor(mx, 32));

        if (!__all(mx <= m_run + THRL2)) {
            const float mnew  = fmaxf(m_run, mx);
            const float alpha = exp2f(m_run - mnew);
            l_run *= alpha;
            m_run = mnew;
            float aq[16];
#pragma unroll
            for (int reg = 0; reg < 16; ++reg)
                aq[reg] = __shfl(alpha, (reg & 3) + 8 * (reg >> 2) + 4 * hi);
#pragma unroll
            for (int dblk = 0; dblk < 4; ++dblk)
#pragma unroll
                for (int reg = 0; reg < 16; ++reg) o[dblk][reg] *= aq[reg];
        }

        float ts = 0.f;
#pragma unroll
        for (int sub = 0; sub < 2; ++sub)
#pragma unroll
            for (int i = 0; i < 16; ++i) {
                const float e = exp2f(sa[sub][i] - m_run);
                sa[sub][i] = e;
                ts += e;
            }
        ts += __shfl_xor(ts, 32);
        l_run += ts;

        // ---- P -> bf16 A-fragments (psi-order: pf[g] = packed p-regs) ----
        short8v pf[4];
#pragma unroll
        for (int g = 0; g < 4; ++g) {
            const int sub = g >> 1, r0 = (g & 1) * 8;
            union { unsigned u[4]; short8v v; } pk;
            pk.u[0] = cvt_pk_bf16(sa[sub][r0 + 0], sa[sub][r0 + 1]);
            pk.u[1] = cvt_pk_bf16(sa[sub][r0 + 2], sa[sub][r0 + 3]);
            pk.u[2] = cvt_pk_bf16(sa[sub][r0 + 4], sa[sub][r0 + 5]);
            pk.u[3] = cvt_pk_bf16(sa[sub][r0 + 6], sa[sub][r0 + 7]);
            pf[g] = pk.v;
        }

        // ---- PV: B frag = one b128 from d-pair-packed V tile ----
        __builtin_amdgcn_s_setprio(1);
#pragma unroll
        for (int dblk = 0; dblk < 4; ++dblk) {
            const int R  = dblk * 16 + (l31 >> 1);
            const char* vr = Vl + R * 256;
            const int dh = (l31 & 1) << 3;
#pragma unroll
            for (int g = 0; g < 4; ++g) {
                const int w = ((dh | (2 * g + hi)) ^ (R & 15)) << 4;
                short8v vf = *reinterpret_cast<const short8v*>(vr + w);
                o[dblk] = __builtin_amdgcn_mfma_f32_32x32x16_bf16(pf[g], vf, o[dblk], 0, 0, 0);
            }
        }
        __builtin_amdgcn_s_setprio(0);

        __syncthreads();       // drains staged loads + LDS reads
        buf ^= 1;
    }

    // ---- merge halves via LDS (aliases staging buffers) ----
    float* smO = (float*)lds;                 // [4][32][128] = 64 KB
    float* smM = (float*)(lds + 65536);       // [4][32]
    float* smL = (float*)(lds + 66048);       // [4][32]

    if (h == 1) {
        if (hi == 0) { smM[qt * 32 + l31] = m_run; smL[qt * 32 + l31] = l_run; }
#pragma unroll
        for (int dblk = 0; dblk < 4; ++dblk)
#pragma unroll
            for (int reg = 0; reg < 16; ++reg) {
                const int qp = (reg & 3) + 8 * (reg >> 2) + 4 * hi;
                smO[(qt * 32 + qp) * 128 + dblk * 32 + l31] = o[dblk][reg];
            }
    }
    __syncthreads();
    if (h == 0) {
        const float m1 = smM[qt * 32 + l31];
        const float l1 = smL[qt * 32 + l31];
        const float mf = fmaxf(m_run, m1);
        const float a0 = exp2f(m_run - mf);
        const float a1 = exp2f(m1 - mf);
        const float li = 1.0f / (l_run * a0 + l1 * a1);
        const float w0 = a0 * li;
        const float w1 = a1 * li;

        float w0q[16], w1q[16];
#pragma unroll
        for (int reg = 0; reg < 16; ++reg) {
            const int qp = (reg & 3) + 8 * (reg >> 2) + 4 * hi;
            w0q[reg] = __shfl(w0, qp);
            w1q[reg] = __shfl(w1, qp);
        }

        float* ob = out + ((size_t)b * SEQ + q0) * DK;
#pragma unroll
        for (int dblk = 0; dblk < 4; ++dblk)
#pragma unroll
            for (int reg = 0; reg < 16; ++reg) {
                const int qp = (reg & 3) + 8 * (reg >> 2) + 4 * hi;
                ob[(size_t)qp * DK + dblk * 32 + l31] =
                    o[dblk][reg] * w0q[reg]
                    + smO[(qt * 32 + qp) * 128 + dblk * 32 + l31] * w1q[reg];
            }
    }
}

// ---------------- fallback (round-1 kernel) if ws too small -----------
__global__ __launch_bounds__(256)
void attn_fwd_slow(const float* __restrict__ q,
                   const float* __restrict__ k,
                   const float* __restrict__ v,
                   float* __restrict__ out)
{
    const int lane = threadIdx.x & 63;
    const int wave = threadIdx.x >> 6;
    const int b    = blockIdx.y;
    const int q0   = blockIdx.x * 64 + wave * 16;
    const int row = lane & 15;
    const int grp = lane >> 4;

    const float* qb = q + ((size_t)b * SEQ + q0) * DK;
    const float* kbp = k + (size_t)b * SEQ * DK;
    const float* vbp = v + (size_t)b * SEQ * DK;

    short8v qf[4];
#pragma unroll
    for (int c = 0; c < 4; ++c) {
        const float* p = qb + row * DK + c * 32 + grp * 8;
        float4 x = *reinterpret_cast<const float4*>(p);
        float4 y = *reinterpret_cast<const float4*>(p + 4);
        short8v t;
        t[0] = f2bf(x.x); t[1] = f2bf(x.y); t[2] = f2bf(x.z); t[3] = f2bf(x.w);
        t[4] = f2bf(y.x); t[5] = f2bf(y.y); t[6] = f2bf(y.z); t[7] = f2bf(y.w);
        qf[c] = t;
    }

    float m_run = -1e30f, l_run = 0.0f;
    float4v o[8];
#pragma unroll
    for (int i = 0; i < 8; ++i) { o[i][0]=0.f; o[i][1]=0.f; o[i][2]=0.f; o[i][3]=0.f; }
    const float scale = 0.08838834764831845f;

    for (int kv0 = 0; kv0 < SEQ; kv0 += 16) {
        short8v kf[4];
        const float* kp0 = kbp + (size_t)(kv0 + row) * DK + grp * 8;
#pragma unroll
        for (int c = 0; c < 4; ++c) {
            const float* p = kp0 + c * 32;
            float4 x = *reinterpret_cast<const float4*>(p);
            float4 y = *reinterpret_cast<const float4*>(p + 4);
            short8v t;
            t[0] = f2bf(x.x); t[1] = f2bf(x.y); t[2] = f2bf(x.z); t[3] = f2bf(x.w);
            t[4] = f2bf(y.x); t[5] = f2bf(y.y); t[6] = f2bf(y.z); t[7] = f2bf(y.w);
            kf[c] = t;
        }
        short8v vf[8];
#pragma unroll
        for (int dblk = 0; dblk < 8; ++dblk) {
            const float* p = vbp + (size_t)(kv0 + 4 * grp) * DK + dblk * 16 + row;
            short b0 = f2bf(p[0]);
            short b1 = f2bf(p[DK]);
            short b2 = f2bf(p[2 * DK]);
            short b3 = f2bf(p[3 * DK]);
            short8v t;
            t[0]=b0; t[1]=b1; t[2]=b2; t[3]=b3; t[4]=b0; t[5]=b1; t[6]=b2; t[7]=b3;
            vf[dblk] = t;
        }
        float4v s; s[0]=0.f; s[1]=0.f; s[2]=0.f; s[3]=0.f;
#pragma unroll
        for (int c = 0; c < 4; ++c)
            s = __builtin_amdgcn_mfma_f32_16x16x32_bf16(kf[c], qf[c], s, 0, 0, 0);

        float sv[4]; float tmax = -1e30f;
#pragma unroll
        for (int r = 0; r < 4; ++r) { sv[r] = s[r] * scale; tmax = fmaxf(tmax, sv[r]); }
        tmax = fmaxf(tmax, __shfl_xor(tmax, 16));
        tmax = fmaxf(tmax, __shfl_xor(tmax, 32));
        const float mnew = fmaxf(m_run, tmax);
        float pr[4]; float tsum = 0.f;
#pragma unroll
        for (int r = 0; r < 4; ++r) { pr[r] = __expf(sv[r] - mnew); tsum += pr[r]; }
        tsum += __shfl_xor(tsum, 16);
        tsum += __shfl_xor(tsum, 32);
        const float alpha = __expf(m_run - mnew);
        l_run = l_run * alpha + tsum;
        m_run = mnew;
        float aq[4];
#pragma unroll
        for (int r = 0; r < 4; ++r) aq[r] = __shfl(alpha, grp * 4 + r);
#pragma unroll
        for (int dblk = 0; dblk < 8; ++dblk)
#pragma unroll
            for (int r = 0; r < 4; ++r) o[dblk][r] *= aq[r];

        short8v pfv;
        pfv[0]=f2bf(pr[0]); pfv[1]=f2bf(pr[1]); pfv[2]=f2bf(pr[2]); pfv[3]=f2bf(pr[3]);
        pfv[4]=0; pfv[5]=0; pfv[6]=0; pfv[7]=0;
#pragma unroll
        for (int dblk = 0; dblk < 8; ++dblk)
            o[dblk] = __builtin_amdgcn_mfma_f32_16x16x32_bf16(pfv, vf[dblk], o[dblk], 0, 0, 0);
    }

    const float linv = 1.0f / l_run;
    float li[4];
#pragma unroll
    for (int r = 0; r < 4; ++r) li[r] = __shfl(linv, grp * 4 + r);
    float* ob = out + ((size_t)b * SEQ + q0) * DK;
#pragma unroll
    for (int dblk = 0; dblk < 8; ++dblk)
#pragma unroll
        for (int r = 0; r < 4; ++r)
            ob[(size_t)(grp * 4 + r) * DK + dblk * 16 + row] = o[dblk][r] * li[r];
}

extern "C" void kernel_launch(void* const* d_in, const int* in_sizes, int n_in,
                              void* d_out, int out_size, void* d_ws, size_t ws_size,
                              hipStream_t stream) {
    const float* q = (const float*)d_in[0];
    const float* k = (const float*)d_in[1];
    const float* v = (const float*)d_in[2];
    float* out = (float*)d_out;

    const size_t kb_bytes = (size_t)BATCH * SEQ * DK * sizeof(short);
    const size_t need = 2 * kb_bytes;

    if (ws_size >= need) {
        short* kb = (short*)d_ws;
        short* vt = (short*)((char*)d_ws + kb_bytes);
        hipLaunchKernelGGL(conv_k_kernel, dim3(2048), dim3(256), 0, stream, k, kb);
        hipLaunchKernelGGL(transpose_v_kernel, dim3(SEQ / 32, DK / 32, BATCH), dim3(256), 0, stream, v, vt);
        hipLaunchKernelGGL(attn_fwd_v13, dim3((SEQ / 128) * BATCH), dim3(512), 0, stream, q, kb, vt, out);
    } else {
        hipLaunchKernelGGL(attn_fwd_slow, dim3(SEQ / 64, BATCH), dim3(256), 0, stream, q, k, v, out);
    }
}

// Round 14
// 63.191 us; speedup vs baseline: 2.2223x; 1.0726x over previous
//
#include <hip/hip_runtime.h>
#include <hip/hip_bf16.h>

#define BATCH 16
#define SEQ   2048
#define DK    128
#define NT    16                    // kv steps per half (KVBLK=64 over 1024)
#define SC2   0.12751744f           // (1/sqrt(128)) * log2(e) -- folded into K prepass
#define THRL2 11.541560f            // defer-max threshold (= 8*log2e)

typedef __attribute__((ext_vector_type(8)))  short short8v;
typedef __attribute__((ext_vector_type(4)))  float float4v;
typedef __attribute__((ext_vector_type(16))) float float16v;

typedef const __attribute__((address_space(1))) unsigned int* gas_t;
typedef __attribute__((address_space(3))) unsigned int* las_t;

__device__ inline void gl_lds16(const void* g, void* l) {
    __builtin_amdgcn_global_load_lds((gas_t)g, (las_t)l, 16, 0, 0);
}

__device__ inline short f2bf(float f) {
    __hip_bfloat16 h = __float2bfloat16(f);
    unsigned short u;
    __builtin_memcpy(&u, &h, sizeof(u));
    return (short)u;
}

__device__ inline unsigned cvt_pk_bf16(float a, float b) {
    unsigned r;
    asm("v_cvt_pk_bf16_f32 %0, %1, %2" : "=v"(r) : "v"(a), "v"(b));
    return r;   // lo = bf16(a), hi = bf16(b)
}

// -------- fused prepass: K fp32 -> bf16*SC2 row-major (blocks 0..2047);
//          V fp32 [b][s][d] -> bf16 Vt [b][d][col] psi-interleaved
//          (blocks 2048..6143).  One launch instead of two.
// psi map per 16-kv group: V[kv] at pos = 8*((kv>>2)&1)+4*((kv>>3)&1)+(kv&3)
// (inverse: kv = (p&3) | ((p>>3)&1)<<2 | ((p>>2)&1)<<3), so each 32x32-MFMA
// PV A-fragment matches one contiguous 16B B-unit.  Each thread emits one
// aligned 8B store (4 bf16, psi-inverse-gathered from the LDS tile) --
// the old version did 4 scattered 2B stores.
__global__ __launch_bounds__(256)
void prepass_kernel(const float* __restrict__ k, const float* __restrict__ v,
                    short* __restrict__ kb, short* __restrict__ vt)
{
    if (blockIdx.x < 2048) {
        size_t i = ((size_t)blockIdx.x * 256 + threadIdx.x) * 8;
        float4 a = *reinterpret_cast<const float4*>(k + i);
        float4 b = *reinterpret_cast<const float4*>(k + i + 4);
        short8v t;
        t[0] = f2bf(a.x * SC2); t[1] = f2bf(a.y * SC2); t[2] = f2bf(a.z * SC2); t[3] = f2bf(a.w * SC2);
        t[4] = f2bf(b.x * SC2); t[5] = f2bf(b.y * SC2); t[6] = f2bf(b.z * SC2); t[7] = f2bf(b.w * SC2);
        *reinterpret_cast<short8v*>(kb + i) = t;
        return;
    }

    __shared__ float tile[32][33];
    const int vb_ = blockIdx.x - 2048;            // 0..4095
    const int b   = vb_ >> 8;                     // 256 blocks/batch
    const int st  = (vb_ >> 2) & 63;              // s-tile (32 kv)
    const int dt  = vb_ & 3;                      // d-tile (32 d)
    const int s0  = st * 32;
    const int d0  = dt * 32;

    const int tx = threadIdx.x & 31;
    const int ty = threadIdx.x >> 5;              // 0..7
    const float* vbp = v + ((size_t)b * SEQ + s0) * DK + d0;
#pragma unroll
    for (int i = 0; i < 4; ++i) {
        int r = ty + 8 * i;
        tile[r][tx] = vbp[(size_t)r * DK + tx];
    }
    __syncthreads();

    // thread -> (d, g2, q): one 8B store of output positions 4q..4q+3
    const int d  = threadIdx.x >> 3;              // 0..31
    const int g2 = (threadIdx.x >> 2) & 1;        // 16-group
    const int qq = threadIdx.x & 3;               // pos quarter
    const int kvb = g2 * 16 + ((qq >> 1) << 2) + ((qq & 1) << 3);  // psi-inverse base

    const float f0 = tile[kvb + 0][d];
    const float f1 = tile[kvb + 1][d];
    const float f2 = tile[kvb + 2][d];
    const float f3 = tile[kvb + 3][d];
    union { unsigned u[2]; unsigned long long ll; } pk;
    pk.u[0] = cvt_pk_bf16(f0, f1);
    pk.u[1] = cvt_pk_bf16(f2, f3);

    short* o = vt + ((size_t)b * DK + d0 + d) * SEQ + s0 + g2 * 16 + qq * 4;
    *reinterpret_cast<unsigned long long*>(o) = pk.ll;
}

// ---------------- main: r13 structure + tree-reduced softmax ----------
// Grid 256 (1D, XCD-decoded): work = (bid&7)*32 + (bid>>3) -> each XCD
// owns 2 batches (K/V 2MB inside its 4MB L2; FETCH == compulsory 16.5MB).
// Block = 512 thr = 8 waves: qt = wave&3 (32 q rows), h = wave>>2 (kv half).
// Grid 256 = 1 block/CU; LDS 128KB = 2buf x 2half x (K16K + V16K).
// 2-phase pipeline: STAGE(t+1 -> buf^1) issued BEFORE compute(t); 1 barrier.
// K tile [64 kv][256B], read swizzle unit ^= (row&15) -> 0 bank conflicts (r13).
// V tile d-pair packed [64 R][256B], slot w = ((d&1)<<3|u)^(R&15), psi-ordered.
// QK^T = mfma32(K, Q); PV = mfma32(P, V); O rows = crow(reg,hi).
// Softmax max/sum now DEPTH-5/10 TREES (were 32-deep serial chains).
// __launch_bounds__(512,2): 108 VGPR measured; r7/r11/r12: any tighter
// occupancy request forces a 64-VGPR target -> full spill.
__global__ __launch_bounds__(512, 2)
void attn_fwd_v14(const float* __restrict__ q,
                  const short* __restrict__ kb,
                  const short* __restrict__ vt,
                  float* __restrict__ out)
{
    __shared__ __align__(16) char lds[131072];

    const int tid  = threadIdx.x;
    const int lane = tid & 63;
    const int wave = tid >> 6;         // 0..7
    const int qt   = wave & 3;
    const int h    = wave >> 2;        // kv half
    const int bid  = blockIdx.x;
    const int work = (bid & 7) * 32 + (bid >> 3);   // XCD-grouped
    const int b    = work >> 4;
    const int q0   = (work & 15) * 128 + qt * 32;

    const int l31 = lane & 31;
    const int hi  = lane >> 5;

    // ---- Q fragments: qf[s] = Q[q0+l31][s*16 + hi*8 + 0..7] ----
    const float* qrow = q + ((size_t)b * SEQ + q0 + l31) * DK + hi * 8;
    short8v qf[8];
#pragma unroll
    for (int s = 0; s < 8; ++s) {
        float4 x = *reinterpret_cast<const float4*>(qrow + s * 16);
        float4 y = *reinterpret_cast<const float4*>(qrow + s * 16 + 4);
        union { unsigned u[4]; short8v v; } pk;
        pk.u[0] = cvt_pk_bf16(x.x, x.y);
        pk.u[1] = cvt_pk_bf16(x.z, x.w);
        pk.u[2] = cvt_pk_bf16(y.x, y.y);
        pk.u[3] = cvt_pk_bf16(y.z, y.w);
        qf[s] = pk.v;
    }

    // ---- staging setup: waves 0,1|4,5 -> K; waves 2,3|6,7 -> V ----
    const char* kB = (const char*)(kb + (size_t)b * SEQ * DK);   // 256B rows
    const char* vB = (const char*)(vt + (size_t)b * DK * SEQ);   // 4096B rows
    const int hkv = h * 1024;

    const char* src[8];
    int dstoff[8];
    long sstep;
    if (qt < 2) {
#pragma unroll
        for (int i = 0; i < 8; ++i) {
            const int kr = qt * 32 + i * 4 + (lane >> 4);        // kv row 0..63
            src[i] = kB + (size_t)(hkv + kr) * 256 + (((lane & 15) ^ (kr & 15)) << 4);
            dstoff[i] = h * 32768 + qt * 8192 + i * 1024;
        }
        sstep = 64 * 256;
    } else {
#pragma unroll
        for (int i = 0; i < 8; ++i) {
            const int R  = (qt - 2) * 32 + i * 4 + (lane >> 4);  // R row 0..63
            const int wx = (lane & 15) ^ (R & 15);
            const int d  = 2 * R + (wx >> 3);
            src[i] = vB + (size_t)d * (SEQ * 2) + (size_t)hkv * 2 + ((wx & 7) << 4);
            dstoff[i] = h * 32768 + 16384 + (qt - 2) * 8192 + i * 1024;
        }
        sstep = 64 * 2;
    }

    float m_run = -1e30f;
    float l_run = 0.0f;
    float16v o[4];
#pragma unroll
    for (int dblk = 0; dblk < 4; ++dblk)
#pragma unroll
        for (int i = 0; i < 16; ++i) o[dblk][i] = 0.f;

    auto STAGE = [&](int bufsel, int t) {
        char* base = lds + bufsel * 65536;
#pragma unroll
        for (int i = 0; i < 8; ++i)
            gl_lds16(src[i] + (size_t)t * sstep, base + dstoff[i]);
    };

    STAGE(0, 0);
    __syncthreads();

    int buf = 0;
    for (int t = 0; t < NT; ++t) {
        if (t + 1 < NT) STAGE(buf ^ 1, t + 1);

        const char* Kl = lds + buf * 65536 + h * 32768;
        const char* Vl = Kl + 16384;
        const char* ka = Kl + l31 * 256;

        // ---- QK^T: 2 subtiles of 32 kv over D=128 ----
        float16v sa[2];
#pragma unroll
        for (int i = 0; i < 16; ++i) { sa[0][i] = 0.f; sa[1][i] = 0.f; }
        __builtin_amdgcn_s_setprio(1);
#pragma unroll
        for (int s = 0; s < 8; ++s) {
            const int un = ((2 * s + hi) ^ (l31 & 15)) << 4;
            short8v kf0 = *reinterpret_cast<const short8v*>(ka + un);
            short8v kf1 = *reinterpret_cast<const short8v*>(ka + 8192 + un);
            sa[0] = __builtin_amdgcn_mfma_f32_32x32x16_bf16(kf0, qf[s], sa[0], 0, 0, 0);
            sa[1] = __builtin_amdgcn_mfma_f32_32x32x16_bf16(kf1, qf[s], sa[1], 0, 0, 0);
        }
        __builtin_amdgcn_s_setprio(0);

        // ---- online softmax (log2-domain; defer-max; tree reductions) ----
        float t16[16];
#pragma unroll
        for (int i = 0; i < 16; ++i) t16[i] = fmaxf(sa[0][i], sa[1][i]);
#pragma unroll
        for (int s2 = 8; s2 > 0; s2 >>= 1)
#pragma unroll
            for (int i = 0; i < s2; ++i) t16[i] = fmaxf(t16[i], t16[i + s2]);
        float mx = fmaxf(t16[0], __shfl_xor(t16[0], 32));

        if (!__all(mx <= m_run + THRL2)) {
            const float mnew  = fmaxf(m_run, mx);
            const float alpha = exp2f(m_run - mnew);
            l_run *= alpha;
            m_run = mnew;
            float aq[16];
#pragma unroll
            for (int reg = 0; reg < 16; ++reg)
                aq[reg] = __shfl(alpha, (reg & 3) + 8 * (reg >> 2) + 4 * hi);
#pragma unroll
            for (int dblk = 0; dblk < 4; ++dblk)
#pragma unroll
                for (int reg = 0; reg < 16; ++reg) o[dblk][reg] *= aq[reg];
        }

        float ts4[4] = {0.f, 0.f, 0.f, 0.f};
#pragma unroll
        for (int sub = 0; sub < 2; ++sub)
#pragma unroll
            for (int i = 0; i < 16; ++i) {
                const float e = exp2f(sa[sub][i] - m_run);
                sa[sub][i] = e;
                ts4[i & 3] += e;
            }
        float ts = (ts4[0] + ts4[1]) + (ts4[2] + ts4[3]);
        ts += __shfl_xor(ts, 32);
        l_run += ts;

        // ---- P -> bf16 A-fragments (psi-order: pf[g] = packed p-regs) ----
        short8v pf[4];
#pragma unroll
        for (int g = 0; g < 4; ++g) {
            const int sub = g >> 1, r0 = (g & 1) * 8;
            union { unsigned u[4]; short8v v; } pk;
            pk.u[0] = cvt_pk_bf16(sa[sub][r0 + 0], sa[sub][r0 + 1]);
            pk.u[1] = cvt_pk_bf16(sa[sub][r0 + 2], sa[sub][r0 + 3]);
            pk.u[2] = cvt_pk_bf16(sa[sub][r0 + 4], sa[sub][r0 + 5]);
            pk.u[3] = cvt_pk_bf16(sa[sub][r0 + 6], sa[sub][r0 + 7]);
            pf[g] = pk.v;
        }

        // ---- PV: B frag = one b128 from d-pair-packed V tile ----
        __builtin_amdgcn_s_setprio(1);
#pragma unroll
        for (int dblk = 0; dblk < 4; ++dblk) {
            const int R  = dblk * 16 + (l31 >> 1);
            const char* vr = Vl + R * 256;
            const int dh = (l31 & 1) << 3;
#pragma unroll
            for (int g = 0; g < 4; ++g) {
                const int w = ((dh | (2 * g + hi)) ^ (R & 15)) << 4;
                short8v vf = *reinterpret_cast<const short8v*>(vr + w);
                o[dblk] = __builtin_amdgcn_mfma_f32_32x32x16_bf16(pf[g], vf, o[dblk], 0, 0, 0);
            }
        }
        __builtin_amdgcn_s_setprio(0);

        __syncthreads();       // drains staged loads + LDS reads
        buf ^= 1;
    }

    // ---- merge halves via LDS (aliases staging buffers) ----
    float* smO = (float*)lds;                 // [4][32][128] = 64 KB
    float* smM = (float*)(lds + 65536);       // [4][32]
    float* smL = (float*)(lds + 66048);       // [4][32]

    if (h == 1) {
        if (hi == 0) { smM[qt * 32 + l31] = m_run; smL[qt * 32 + l31] = l_run; }
#pragma unroll
        for (int dblk = 0; dblk < 4; ++dblk)
#pragma unroll
            for (int reg = 0; reg < 16; ++reg) {
                const int qp = (reg & 3) + 8 * (reg >> 2) + 4 * hi;
                smO[(qt * 32 + qp) * 128 + dblk * 32 + l31] = o[dblk][reg];
            }
    }
    __syncthreads();
    if (h == 0) {
        const float m1 = smM[qt * 32 + l31];
        const float l1 = smL[qt * 32 + l31];
        const float mf = fmaxf(m_run, m1);
        const float a0 = exp2f(m_run - mf);
        const float a1 = exp2f(m1 - mf);
        const float li = 1.0f / (l_run * a0 + l1 * a1);
        const float w0 = a0 * li;
        const float w1 = a1 * li;

        float w0q[16], w1q[16];
#pragma unroll
        for (int reg = 0; reg < 16; ++reg) {
            const int qp = (reg & 3) + 8 * (reg >> 2) + 4 * hi;
            w0q[reg] = __shfl(w0, qp);
            w1q[reg] = __shfl(w1, qp);
        }

        float* ob = out + ((size_t)b * SEQ + q0) * DK;
#pragma unroll
        for (int dblk = 0; dblk < 4; ++dblk)
#pragma unroll
            for (int reg = 0; reg < 16; ++reg) {
                const int qp = (reg & 3) + 8 * (reg >> 2) + 4 * hi;
                ob[(size_t)qp * DK + dblk * 32 + l31] =
                    o[dblk][reg] * w0q[reg]
                    + smO[(qt * 32 + qp) * 128 + dblk * 32 + l31] * w1q[reg];
            }
    }
}

// ---------------- fallback (round-1 kernel) if ws too small -----------
__global__ __launch_bounds__(256)
void attn_fwd_slow(const float* __restrict__ q,
                   const float* __restrict__ k,
                   const float* __restrict__ v,
                   float* __restrict__ out)
{
    const int lane = threadIdx.x & 63;
    const int wave = threadIdx.x >> 6;
    const int b    = blockIdx.y;
    const int q0   = blockIdx.x * 64 + wave * 16;
    const int row = lane & 15;
    const int grp = lane >> 4;

    const float* qb = q + ((size_t)b * SEQ + q0) * DK;
    const float* kbp = k + (size_t)b * SEQ * DK;
    const float* vbp = v + (size_t)b * SEQ * DK;

    short8v qf[4];
#pragma unroll
    for (int c = 0; c < 4; ++c) {
        const float* p = qb + row * DK + c * 32 + grp * 8;
        float4 x = *reinterpret_cast<const float4*>(p);
        float4 y = *reinterpret_cast<const float4*>(p + 4);
        short8v t;
        t[0] = f2bf(x.x); t[1] = f2bf(x.y); t[2] = f2bf(x.z); t[3] = f2bf(x.w);
        t[4] = f2bf(y.x); t[5] = f2bf(y.y); t[6] = f2bf(y.z); t[7] = f2bf(y.w);
        qf[c] = t;
    }

    float m_run = -1e30f, l_run = 0.0f;
    float4v o[8];
#pragma unroll
    for (int i = 0; i < 8; ++i) { o[i][0]=0.f; o[i][1]=0.f; o[i][2]=0.f; o[i][3]=0.f; }
    const float scale = 0.08838834764831845f;

    for (int kv0 = 0; kv0 < SEQ; kv0 += 16) {
        short8v kf[4];
        const float* kp0 = kbp + (size_t)(kv0 + row) * DK + grp * 8;
#pragma unroll
        for (int c = 0; c < 4; ++c) {
            const float* p = kp0 + c * 32;
            float4 x = *reinterpret_cast<const float4*>(p);
            float4 y = *reinterpret_cast<const float4*>(p + 4);
            short8v t;
            t[0] = f2bf(x.x); t[1] = f2bf(x.y); t[2] = f2bf(x.z); t[3] = f2bf(x.w);
            t[4] = f2bf(y.x); t[5] = f2bf(y.y); t[6] = f2bf(y.z); t[7] = f2bf(y.w);
            kf[c] = t;
        }
        short8v vf[8];
#pragma unroll
        for (int dblk = 0; dblk < 8; ++dblk) {
            const float* p = vbp + (size_t)(kv0 + 4 * grp) * DK + dblk * 16 + row;
            short b0 = f2bf(p[0]);
            short b1 = f2bf(p[DK]);
            short b2 = f2bf(p[2 * DK]);
            short b3 = f2bf(p[3 * DK]);
            short8v t;
            t[0]=b0; t[1]=b1; t[2]=b2; t[3]=b3; t[4]=b0; t[5]=b1; t[6]=b2; t[7]=b3;
            vf[dblk] = t;
        }
        float4v s; s[0]=0.f; s[1]=0.f; s[2]=0.f; s[3]=0.f;
#pragma unroll
        for (int c = 0; c < 4; ++c)
            s = __builtin_amdgcn_mfma_f32_16x16x32_bf16(kf[c], qf[c], s, 0, 0, 0);

        float sv[4]; float tmax = -1e30f;
#pragma unroll
        for (int r = 0; r < 4; ++r) { sv[r] = s[r] * scale; tmax = fmaxf(tmax, sv[r]); }
        tmax = fmaxf(tmax, __shfl_xor(tmax, 16));
        tmax = fmaxf(tmax, __shfl_xor(tmax, 32));
        const float mnew = fmaxf(m_run, tmax);
        float pr[4]; float tsum = 0.f;
#pragma unroll
        for (int r = 0; r < 4; ++r) { pr[r] = __expf(sv[r] - mnew); tsum += pr[r]; }
        tsum += __shfl_xor(tsum, 16);
        tsum += __shfl_xor(tsum, 32);
        const float alpha = __expf(m_run - mnew);
        l_run = l_run * alpha + tsum;
        m_run = mnew;
        float aq[4];
#pragma unroll
        for (int r = 0; r < 4; ++r) aq[r] = __shfl(alpha, grp * 4 + r);
#pragma unroll
        for (int dblk = 0; dblk < 8; ++dblk)
#pragma unroll
            for (int r = 0; r < 4; ++r) o[dblk][r] *= aq[r];

        short8v pfv;
        pfv[0]=f2bf(pr[0]); pfv[1]=f2bf(pr[1]); pfv[2]=f2bf(pr[2]); pfv[3]=f2bf(pr[3]);
        pfv[4]=0; pfv[5]=0; pfv[6]=0; pfv[7]=0;
#pragma unroll
        for (int dblk = 0; dblk < 8; ++dblk)
            o[dblk] = __builtin_amdgcn_mfma_f32_16x16x32_bf16(pfv, vf[dblk], o[dblk], 0, 0, 0);
    }

    const float linv = 1.0f / l_run;
    float li[4];
#pragma unroll
    for (int r = 0; r < 4; ++r) li[r] = __shfl(linv, grp * 4 + r);
    float* ob = out + ((size_t)b * SEQ + q0) * DK;
#pragma unroll
    for (int dblk = 0; dblk < 8; ++dblk)
#pragma unroll
        for (int r = 0; r < 4; ++r)
            ob[(size_t)(grp * 4 + r) * DK + dblk * 16 + row] = o[dblk][r] * li[r];
}

extern "C" void kernel_launch(void* const* d_in, const int* in_sizes, int n_in,
                              void* d_out, int out_size, void* d_ws, size_t ws_size,
                              hipStream_t stream) {
    const float* q = (const float*)d_in[0];
    const float* k = (const float*)d_in[1];
    const float* v = (const float*)d_in[2];
    float* out = (float*)d_out;

    const size_t kb_bytes = (size_t)BATCH * SEQ * DK * sizeof(short);
    const size_t need = 2 * kb_bytes;

    if (ws_size >= need) {
        short* kbuf = (short*)d_ws;
        short* vtbuf = (short*)((char*)d_ws + kb_bytes);
        hipLaunchKernelGGL(prepass_kernel, dim3(2048 + 4096), dim3(256), 0, stream, k, v, kbuf, vtbuf);
        hipLaunchKernelGGL(attn_fwd_v14, dim3((SEQ / 128) * BATCH), dim3(512), 0, stream, q, kbuf, vtbuf, out);
    } else {
        hipLaunchKernelGGL(attn_fwd_slow, dim3(SEQ / 64, BATCH), dim3(256), 0, stream, q, k, v, out);
    }
}